// Round 5
// baseline (53.641 us; speedup 1.0000x reference)
//
#include <hip/hip_runtime.h>

#define HW     (768*768)       // 589824 pixels per plane
#define N4     (HW/4)          // 147456 float4 groups per plane
#define MAXI   33
#define B_IMG  8
#define NTHR   256
#define NBLK   2048            // exactly 8 blocks/CU on 256 CUs, single round
#define GPB    576             // groups per block: 2*256 vector + 64 scalar-tail groups
#define BPI    256             // blocks per image (N4/GPB)

// ---------- Pass 1: ballot histogram of valid ids + ci-fused widx byte plane ----------
// count-id  c = (ign==0) ? id : 33     (counts need validity only)
// weight-id e = (ci!=0)  ? c  : 33     (error sums need validity AND ci)
__global__ __launch_bounds__(NTHR, 8) void pass1_count(
    const int* __restrict__ inst, const int* __restrict__ ign,
    const float* __restrict__ gci,
    int* __restrict__ g_counts, uchar4* __restrict__ wbp, int write_bytes)
{
    const int bid  = blockIdx.x;
    const int b    = bid / BPI;
    const int lane = threadIdx.x & 63;
    const int wv   = threadIdx.x >> 6;
    const int4*   ip  = (const int4*)inst;
    const int4*   gp  = (const int4*)ign;
    const float4* cip = (const float4*)gci;

    int acc = 0;   // count for bin == lane (lanes 0..32 hold bins)

#define HIST4(c0, c1, c2, c3) \
    for (int k = 0; k < MAXI; ++k) { \
        int cc = __popcll(__ballot((c0) == k)) + __popcll(__ballot((c1) == k)) \
               + __popcll(__ballot((c2) == k)) + __popcll(__ballot((c3) == k)); \
        acc += (lane == k) ? cc : 0; \
    }

    #pragma unroll
    for (int j = 0; j < 2; ++j) {
        const int g = bid * GPB + j * NTHR + threadIdx.x;
        int4   id4 = ip[g];
        int4   g4  = gp[g];
        float4 ci  = cip[g];
        int c0 = (g4.x == 0) ? id4.x : MAXI;
        int c1 = (g4.y == 0) ? id4.y : MAXI;
        int c2 = (g4.z == 0) ? id4.z : MAXI;
        int c3 = (g4.w == 0) ? id4.w : MAXI;
        if (write_bytes) {
            int e0 = (ci.x != 0.f) ? c0 : MAXI;
            int e1 = (ci.y != 0.f) ? c1 : MAXI;
            int e2 = (ci.z != 0.f) ? c2 : MAXI;
            int e3 = (ci.w != 0.f) ? c3 : MAXI;
            wbp[g] = make_uchar4((unsigned char)e0, (unsigned char)e1,
                                 (unsigned char)e2, (unsigned char)e3);
        }
        HIST4(c0, c1, c2, c3)
    }
    // scalar tail: 256 pixels, one per thread
    {
        const int p  = (bid * GPB + 2 * NTHR) * 4 + threadIdx.x;
        int id  = inst[p];
        int gg  = ign[p];
        float c = gci[p];
        int cc0 = (gg == 0) ? id : MAXI;
        if (write_bytes) {
            int e = (c != 0.f) ? cc0 : MAXI;
            ((unsigned char*)wbp)[p] = (unsigned char)e;
        }
        for (int k = 0; k < MAXI; ++k) {
            int cnt = __popcll(__ballot(cc0 == k));
            acc += (lane == k) ? cnt : 0;
        }
    }
#undef HIST4

    __shared__ int s_cnt[NTHR / 64][MAXI];
    if (lane < MAXI) s_cnt[wv][lane] = acc;
    __syncthreads();
    if (threadIdx.x < MAXI) {
        int t = 0;
        #pragma unroll
        for (int w = 0; w < NTHR / 64; ++w) t += s_cnt[w][threadIdx.x];
        atomicAdd(&g_counts[b * MAXI + threadIdx.x], t);
    }
}

// ---------- Pass 2: weighted L1 accumulate (7 streams), LDS weight LUT ----------
template<int SRC>   // 1 = byte plane, 0 = fallback raw inst/ign/ci
__global__ __launch_bounds__(NTHR, 8) void pass2_loss(
    const float* __restrict__ pred, const uchar4* __restrict__ wbp,
    const int* __restrict__ inst, const int* __restrict__ ign,
    const float* __restrict__ gci,
    const float* __restrict__ gtR, const float* __restrict__ gts,
    const float* __restrict__ gtc,
    const int* __restrict__ g_counts, float* __restrict__ partials)
{
    const int bid = blockIdx.x;
    const int b   = bid / BPI;

    __shared__ float lut[MAXI + 1];
    __shared__ float s_ninv;
    if (threadIdx.x == 0) {
        int n = 0;
        for (int k = 1; k < MAXI; ++k) n += (g_counts[b * MAXI + k] > 0) ? 1 : 0;
        s_ninv = 1.0f / fmaxf((float)n, 1.0f);
    }
    __syncthreads();
    if (threadIdx.x < MAXI) {
        float sz = fmaxf((float)g_counts[b * MAXI + threadIdx.x], 1.0f);
        float f = 1.0f / sz;
        if (threadIdx.x > 0) f *= s_ninv;
        lut[threadIdx.x] = f;
    }
    if (threadIdx.x == MAXI) lut[MAXI] = 0.0f;
    __syncthreads();

    const float4* p0  = (const float4*)pred + (size_t)(b * 3 + 0) * N4;
    const float4* p1  = (const float4*)pred + (size_t)(b * 3 + 1) * N4;
    const float4* p2  = (const float4*)pred + (size_t)(b * 3 + 2) * N4;
    const float4* Rp  = (const float4*)gtR;
    const float4* sp  = (const float4*)gts;
    const float4* cp  = (const float4*)gtc;
    const int4*   ipp = (const int4*)inst;
    const int4*   gpp = (const int4*)ign;
    const float4* cip = (const float4*)gci;

    float as = 0.f, ac = 0.f, ar = 0.f;

    #pragma unroll
    for (int j = 0; j < 2; ++j) {
        const int g  = bid * GPB + j * NTHR + threadIdx.x;
        const int lg = g - b * N4;
        float4 a  = p0[lg];
        float4 bb = p1[lg];
        float4 rr = p2[lg];
        float4 R  = Rp[g];
        float4 si = sp[g];
        float4 co = cp[g];
        int w0, w1, w2, w3;
        if constexpr (SRC) {
            uchar4 u = wbp[g];
            w0 = u.x; w1 = u.y; w2 = u.z; w3 = u.w;
        } else {
            int4 id4 = ipp[g]; int4 g4 = gpp[g]; float4 ci = cip[g];
            w0 = (g4.x == 0 && ci.x != 0.f) ? id4.x : MAXI;
            w1 = (g4.y == 0 && ci.y != 0.f) ? id4.y : MAXI;
            w2 = (g4.z == 0 && ci.z != 0.f) ? id4.z : MAXI;
            w3 = (g4.w == 0 && ci.w != 0.f) ? id4.w : MAXI;
        }
        float f0 = lut[w0], f1 = lut[w1], f2 = lut[w2], f3 = lut[w3];
        as += f0 * fabsf(a.x - si.x) + f1 * fabsf(a.y - si.y)
            + f2 * fabsf(a.z - si.z) + f3 * fabsf(a.w - si.w);
        ac += f0 * fabsf(bb.x - co.x) + f1 * fabsf(bb.y - co.y)
            + f2 * fabsf(bb.z - co.z) + f3 * fabsf(bb.w - co.w);
        ar += f0 * fabsf(rr.x - __logf(R.x + 1.f)) + f1 * fabsf(rr.y - __logf(R.y + 1.f))
            + f2 * fabsf(rr.z - __logf(R.z + 1.f)) + f3 * fabsf(rr.w - __logf(R.w + 1.f));
    }
    // scalar tail: one pixel per thread
    {
        const int p  = (bid * GPB + 2 * NTHR) * 4 + threadIdx.x;
        const int lp = p - b * HW;
        float pa = pred[(size_t)(b * 3 + 0) * HW + lp];
        float pb = pred[(size_t)(b * 3 + 1) * HW + lp];
        float pr = pred[(size_t)(b * 3 + 2) * HW + lp];
        float R  = gtR[p];
        float si = gts[p];
        float co = gtc[p];
        int w;
        if constexpr (SRC) {
            w = ((const unsigned char*)wbp)[p];
        } else {
            w = (ign[p] == 0 && gci[p] != 0.f) ? inst[p] : MAXI;
        }
        float f = lut[w];
        as += f * fabsf(pa - si);
        ac += f * fabsf(pb - co);
        ar += f * fabsf(pr - __logf(R + 1.f));
    }

    #pragma unroll
    for (int o = 32; o > 0; o >>= 1) {
        as += __shfl_down(as, o);
        ac += __shfl_down(ac, o);
        ar += __shfl_down(ar, o);
    }
    __shared__ float sred[3][NTHR / 64];
    const int wv = threadIdx.x >> 6, lane = threadIdx.x & 63;
    if (lane == 0) { sred[0][wv] = as; sred[1][wv] = ac; sred[2][wv] = ar; }
    __syncthreads();
    if (threadIdx.x == 0) {
        float ts = 0.f, tc = 0.f, tr = 0.f;
        #pragma unroll
        for (int w = 0; w < NTHR / 64; ++w) { ts += sred[0][w]; tc += sred[1][w]; tr += sred[2][w]; }
        float* pp = partials + (size_t)bid * 3;
        pp[0] = ts; pp[1] = tc; pp[2] = tr;
    }
}

// ---------- Finalize: deterministic reduce of 256 block-partials per image ----------
__global__ __launch_bounds__(NTHR) void finalize(
    const float* __restrict__ partials, float* __restrict__ out)
{
    const int b = blockIdx.x;
    const float* pp = partials + (size_t)(b * BPI + threadIdx.x) * 3;
    float s = pp[0], c = pp[1], r = pp[2];
    #pragma unroll
    for (int o = 32; o > 0; o >>= 1) {
        s += __shfl_down(s, o);
        c += __shfl_down(c, o);
        r += __shfl_down(r, o);
    }
    __shared__ float sr[3][NTHR / 64];
    const int wv = threadIdx.x >> 6, lane = threadIdx.x & 63;
    if (lane == 0) { sr[0][wv] = s; sr[1][wv] = c; sr[2][wv] = r; }
    __syncthreads();
    if (threadIdx.x == 0) {
        float ts = 0.f, tc = 0.f, tr = 0.f;
        #pragma unroll
        for (int w = 0; w < NTHR / 64; ++w) { ts += sr[0][w]; tc += sr[1][w]; tr += sr[2][w]; }
        float tot = ts + tc + tr;
        out[     b] = tot;
        out[ 8 + b] = 0.f;
        out[16 + b] = tot;
        out[24 + b] = 0.f;
        out[32 + b] = ts;
        out[40 + b] = tc;
        out[48 + b] = tr;
        out[56 + b] = 0.f;
    }
}

extern "C" void kernel_launch(void* const* d_in, const int* in_sizes, int n_in,
                              void* d_out, int out_size, void* d_ws, size_t ws_size,
                              hipStream_t stream) {
    const float* pred = (const float*)d_in[0];
    const int*   inst = (const int*)d_in[1];
    // d_in[2] = label (unused by the reference)
    const float* gtR  = (const float*)d_in[3];
    const float* gts  = (const float*)d_in[4];
    const float* gtc  = (const float*)d_in[5];
    const float* gci  = (const float*)d_in[6];
    const int*   ign  = (const int*)d_in[7];
    float* out = (float*)d_out;

    int*    g_counts = (int*)d_ws;
    float*  partials = (float*)((char*)d_ws + 4096);       // 2048*3*4 = 24576 B
    uchar4* wbp      = (uchar4*)((char*)d_ws + 65536);     // 4.72 MB byte plane
    const size_t need_bytes = 65536 + (size_t)B_IMG * HW;
    const int use_bytes = (ws_size >= need_bytes) ? 1 : 0;

    hipMemsetAsync(g_counts, 0, B_IMG * MAXI * sizeof(int), stream);

    pass1_count<<<NBLK, NTHR, 0, stream>>>(inst, ign, gci, g_counts, wbp, use_bytes);
    if (use_bytes)
        pass2_loss<1><<<NBLK, NTHR, 0, stream>>>(pred, wbp, inst, ign, gci, gtR, gts, gtc, g_counts, partials);
    else
        pass2_loss<0><<<NBLK, NTHR, 0, stream>>>(pred, wbp, inst, ign, gci, gtR, gts, gtc, g_counts, partials);
    finalize<<<B_IMG, NTHR, 0, stream>>>(partials, out);
}